// Round 9
// baseline (26.380 us; speedup 1.0000x reference)
//
#include <hip/hip_runtime.h>

// Wiener-Hammerstein, exact chunk-state passing, NO u-LDS (direct loads).
//   y1 = IIR(b1,a1,n_k=1)(u);  v = whf(y1);  out = IIR(b2,a2,n_k=0)(v)
// R5-R8 ledger: 5 structures all 21.3-24.7us; occupancy/pipeline-invariant.
// Last real lever: at CH=32 a lane's 32 samples = two FULL 64B lines, so
// direct float4 global loads have no line-level over-fetch (R2's 4x amp
// was the CHUNK=64 256B-stride pattern). Removes 17 ds-ops + ~32 cvt +
// 2 barriers per thread vs R6. Outputs still staged through swizzled LDS
// (R1: strided direct stores cost 4.6x write amplification).
// Exact-state at CH=32 (proven R6, absmax 3.9e-3):
//   E1 = D1[c-1] + A1*D1[c-2],                A1 = C1^32 (trunc rho1^64 ~7e-9)
//   E2 = D2[c-1] + A2*D2[c-2] + A2q*D2[c-3],  A2 = C2^32, A2q = C2^64
//   v-tails from local y1 tails (err ~1e-3 << 2.4e-2 budget).

constexpr int T_LEN = 16384;
constexpr int NTH   = 512;
constexpr int NCH   = 512;   // chunks per row (CH = 32)

__global__ __launch_bounds__(NTH, 4)
void whsys_kernel(const float* __restrict__ u,
                  const float* __restrict__ b1v, const float* __restrict__ a1v,
                  const float* __restrict__ b2v, const float* __restrict__ a2v,
                  float* __restrict__ out)
{
    // o_st[k][q ^ (k&7)]: whole-row output staging. Writes (fixed q, lanes k)
    // and reads (8-lane groups sweep q at fixed k) both cycle all 8
    // bank-quads -> b128 floor both ways (R6-proven pattern, single pass).
    __shared__ float4 o_st[NCH * 8];     // 64 KB
    __shared__ float4 d1s[NCH + 2];      // stage-1 chunk-final states (+pad)
    __shared__ float4 d2s[NCH + 3];      // stage-2 chunk-final states (+pad)
    __shared__ float2 vts[NCH + 1];      // v tails (v[-2], v[-1]) (+pad)

    const int c = threadIdx.x;
    const float4* __restrict__ urow4 =
        reinterpret_cast<const float4*>(u + (size_t)blockIdx.x * T_LEN);
    float4* __restrict__ orow4 =
        reinterpret_cast<float4*>(out + (size_t)blockIdx.x * T_LEN);

    const float b10=b1v[0], b11=b1v[1], b12=b1v[2];
    const float a10=a1v[0], a11=a1v[1], a12=a1v[2];
    const float b20=b2v[0], b21=b2v[1], b22=b2v[2];
    const float a20=a2v[0], a21=a2v[1], a22=a2v[2];

    if (c < 2) d1s[c] = make_float4(0,0,0,0);
    if (c < 3) d2s[c] = make_float4(0,0,0,0);
    if (c == 0) vts[0] = make_float2(0,0);

    // ---- A1 = C1^32, A2 = C2^32 (5 squarings), A2q = C2^64 -----------------
    float A1[9] = {-a10,-a11,-a12, 1.f,0.f,0.f, 0.f,1.f,0.f};
    float A2[9] = {-a20,-a21,-a22, 1.f,0.f,0.f, 0.f,1.f,0.f};
    float A2q[9];
    #pragma unroll
    for (int it = 0; it < 5; ++it) {
        float B1[9], B2[9];
        #pragma unroll
        for (int i = 0; i < 3; ++i)
            #pragma unroll
            for (int j = 0; j < 3; ++j) {
                B1[i*3+j] = fmaf(A1[i*3], A1[j], fmaf(A1[i*3+1], A1[3+j], A1[i*3+2]*A1[6+j]));
                B2[i*3+j] = fmaf(A2[i*3], A2[j], fmaf(A2[i*3+1], A2[3+j], A2[i*3+2]*A2[6+j]));
            }
        #pragma unroll
        for (int i = 0; i < 9; ++i) { A1[i] = B1[i]; A2[i] = B2[i]; }
    }
    #pragma unroll
    for (int i = 0; i < 3; ++i)
        #pragma unroll
        for (int j = 0; j < 3; ++j)
            A2q[i*3+j] = fmaf(A2[i*3], A2[j], fmaf(A2[i*3+1], A2[3+j], A2[i*3+2]*A2[6+j]));

    auto whf = [](float y) -> float {   // -elu(-10/11 y) = med3(ky, 1-e^-ky, 0)
        const float t1 = 0.9090909090909091f * y;
        const float e  = 1.f - __expf(-t1);
        return __builtin_amdgcn_fmed3f(t1, e, 0.f);
    };

    float arr[32];                      // y1 local, overwritten by y2 local

    // ---- pass 1: stage-1 local (zero y-init, exact u), DIRECT loads --------
    {
        float u1 = 0.f, u2 = 0.f, u3 = 0.f;
        if (c > 0) {                    // u[32c-4 .. 32c-1]
            const float4 tq = urow4[8*c - 1];
            u1 = tq.w; u2 = tq.z; u3 = tq.y;
        }
        float y1 = 0.f, y2 = 0.f, y3 = 0.f;
        #pragma unroll
        for (int m = 0; m < 8; ++m) {
            const float4 uu = urow4[8*c + m];
            const float us[4] = {uu.x, uu.y, uu.z, uu.w};
            #pragma unroll
            for (int e = 0; e < 4; ++e) {
                const float x = fmaf(b12,u3, fmaf(b11,u2, b10*u1));
                const float y = fmaf(-a10,y1, fmaf(-a11,y2, fmaf(-a12,y3, x)));
                arr[m*4+e] = y;
                u3=u2; u2=u1; u1=us[e];
                y3=y2; y2=y1; y1=y;
            }
        }
        d1s[c + 2] = make_float4(y1, y2, y3, 0.f);     // y[31],[30],[29]
        vts[c + 1] = make_float2(whf(y2), whf(y1));    // (v[-2], v[-1])
    }
    __syncthreads();   // B1

    // ---- pass 2: exact y1 + whf + stage-2 local (fused) --------------------
    {
        const float4 P = d1s[c + 1], Q = d1s[c];       // E1 = P + A1*Q
        float h1 = fmaf(A1[0],Q.x, fmaf(A1[1],Q.y, fmaf(A1[2],Q.z, P.x)));
        float h2 = fmaf(A1[3],Q.x, fmaf(A1[4],Q.y, fmaf(A1[5],Q.z, P.y)));
        float h3 = fmaf(A1[6],Q.x, fmaf(A1[7],Q.y, fmaf(A1[8],Q.z, P.z)));
        const float2 vt = vts[c];
        float v1r = vt.y, v2r = vt.x;
        float z1 = 0.f, z2 = 0.f, z3 = 0.f;
        #pragma unroll
        for (int j = 0; j < 32; ++j) {
            const float hn = fmaf(-a10,h1, fmaf(-a11,h2, -a12*h3));
            h3=h2; h2=h1; h1=hn;
            const float v = whf(arr[j] + hn);
            const float x = fmaf(b22,v2r, fmaf(b21,v1r, b20*v));
            const float z = fmaf(-a20,z1, fmaf(-a21,z2, fmaf(-a22,z3, x)));
            v2r=v1r; v1r=v;
            z3=z2; z2=z1; z1=z;
            arr[j] = z;                                // y2 local
        }
        d2s[c + 3] = make_float4(z1, z2, z3, 0.f);
    }
    __syncthreads();   // B2

    // ---- pass 3: E2 = D2[c-1] + A2*D2[c-2] + A2q*D2[c-3]; correct ----------
    {
        const float4 R = d2s[c + 2], S = d2s[c + 1], Tt = d2s[c];
        float g1 = fmaf(A2[0],S.x, fmaf(A2[1],S.y, fmaf(A2[2],S.z,
                   fmaf(A2q[0],Tt.x, fmaf(A2q[1],Tt.y, fmaf(A2q[2],Tt.z, R.x))))));
        float g2 = fmaf(A2[3],S.x, fmaf(A2[4],S.y, fmaf(A2[5],S.z,
                   fmaf(A2q[3],Tt.x, fmaf(A2q[4],Tt.y, fmaf(A2q[5],Tt.z, R.y))))));
        float g3 = fmaf(A2[6],S.x, fmaf(A2[7],S.y, fmaf(A2[8],S.z,
                   fmaf(A2q[6],Tt.x, fmaf(A2q[7],Tt.y, fmaf(A2q[8],Tt.z, R.z))))));
        #pragma unroll
        for (int j = 0; j < 32; ++j) {
            const float gn = fmaf(-a20,g1, fmaf(-a21,g2, -a22*g3));
            g3=g2; g2=g1; g1=gn;
            arr[j] += gn;
        }
    }

    // ---- out staging (swizzled) + fully-coalesced stores --------------------
    #pragma unroll
    for (int q8 = 0; q8 < 8; ++q8)
        o_st[c * 8 + (q8 ^ (c & 7))] =
            make_float4(arr[4*q8], arr[4*q8+1], arr[4*q8+2], arr[4*q8+3]);
    __syncthreads();   // B3
    #pragma unroll
    for (int it = 0; it < 8; ++it) {
        const int f = it * 512 + c;              // 4096 float4 per row
        const int k = f >> 3, q = f & 7;
        orow4[f] = o_st[k * 8 + (q ^ (k & 7))];
    }
}

extern "C" void kernel_launch(void* const* d_in, const int* in_sizes, int n_in,
                              void* d_out, int out_size, void* d_ws, size_t ws_size,
                              hipStream_t stream) {
    const float* u  = (const float*)d_in[0];
    const float* b1 = (const float*)d_in[1];
    const float* a1 = (const float*)d_in[2];
    const float* b2 = (const float*)d_in[3];
    const float* a2 = (const float*)d_in[4];
    float* out = (float*)d_out;

    const int B = in_sizes[0] / T_LEN;   // 512
    whsys_kernel<<<B, NTH, 0, stream>>>(u, b1, a1, b2, a2, out);
}

// Round 11
// 18.079 us; speedup vs baseline: 1.4592x; 1.4592x over previous
//
#include <hip/hip_runtime.h>
#include <hip/hip_fp16.h>

// Wiener-Hammerstein, exact chunk-state passing, CHUNK=32 / 512 threads.
// == R6 (best measured: 21.34us, absmax 3.9e-3) + non-temporal output stores.
// R9 falsified removing u-LDS (26.4us: 128B-stride lane loads thrash L1);
// R7 falsified block-stagger; R8 falsified intra-kernel pipelining. This is
// the ledger's best structure; NT stores keep the 33.5MB output stream from
// evicting the L2/L3 read working set. (R10 fix: nontemporal builtin needs a
// native ext_vector type, not HIP_vector_type.)
//   y1 = IIR(b1,a1,n_k=1)(u);  v = whf(y1);  out = IIR(b2,a2,n_k=0)(v)
// Exact-state at CH=32: E1 = D1[c-1] + A1*D1[c-2]  (A1 = C1^32, trunc
// rho1^64 ~ 7e-9); E2 = D2[c-1] + A2*D2[c-2] + A2q*D2[c-3] (A2 = C2^32,
// A2q = C2^64, trunc rho2^96 ~ 4e-5). v-tails from LOCAL y1 tails
// (err rho1^30*|E1| ~ 1e-3 << 2.4e-2 budget).

constexpr int T_LEN = 16384;
constexpr int NTH   = 512;
constexpr int NCH   = 512;   // chunks per row (CHUNK = 32)

typedef float floatx4 __attribute__((ext_vector_type(4)));

__global__ __launch_bounds__(NTH, 4)
void whsys_kernel(const float* __restrict__ u,
                  const float* __restrict__ b1v, const float* __restrict__ a1v,
                  const float* __restrict__ b2v, const float* __restrict__ a2v,
                  float* __restrict__ out)
{
    // u4[m][k64 ^ m] (uint2 = f16x4): samples 4m..4m+3 of 64-sample seg k64
    // (R5-verified conflict-free layout). o_st ALIASES u4 (dead after pass1):
    // float4 [256 chunks][8 quads], slot q ^ (chunk&7) -> b128 floor both ways.
    __shared__ __align__(16) unsigned char smem[32768];
    uint2*  u4   = reinterpret_cast<uint2*>(smem);
    float4* o_st = reinterpret_cast<float4*>(smem);
    __shared__ float4 d1s[NCH + 2];   // stage-1 local tails (+2 zero pad)
    __shared__ float4 d2s[NCH + 3];   // stage-2 local tails (+3 zero pad)
    __shared__ float2 vts[NCH + 1];   // v tails (v[-2], v[-1]) (+1 zero pad)

    const int c = threadIdx.x;
    const float* __restrict__ urow = u   + (size_t)blockIdx.x * T_LEN;
    float*       __restrict__ orow = out + (size_t)blockIdx.x * T_LEN;

    const float b10=b1v[0], b11=b1v[1], b12=b1v[2];
    const float a10=a1v[0], a11=a1v[1], a12=a1v[2];
    const float b20=b2v[0], b21=b2v[1], b22=b2v[2];
    const float a20=a2v[0], a21=a2v[1], a22=a2v[2];

    // ---- phase 0: coalesced float4 load -> f16x4 pack -> swizzled LDS ------
    #pragma unroll
    for (int q = 0; q < 8; ++q) {
        const int t0 = q * 2048 + c * 4;
        const float4 v = *reinterpret_cast<const float4*>(urow + t0);
        const int k64 = q * 32 + (c >> 4);
        const int m   = c & 15;
        const __half2 h01 = __floats2half2_rn(v.x, v.y);
        const __half2 h23 = __floats2half2_rn(v.z, v.w);
        uint2 pk;
        pk.x = __builtin_bit_cast(unsigned int, h01);
        pk.y = __builtin_bit_cast(unsigned int, h23);
        u4[m * 256 + (k64 ^ m)] = pk;
    }
    if (c < 2) d1s[c] = make_float4(0,0,0,0);
    if (c < 3) d2s[c] = make_float4(0,0,0,0);
    if (c == 0) vts[0] = make_float2(0,0);

    // ---- A1 = C1^32 (5 squarings), A2 = C2^32, A2q = C2^64 -----------------
    float A1[9] = {-a10,-a11,-a12, 1.f,0.f,0.f, 0.f,1.f,0.f};
    float A2[9] = {-a20,-a21,-a22, 1.f,0.f,0.f, 0.f,1.f,0.f};
    float A2q[9];
    #pragma unroll
    for (int it = 0; it < 5; ++it) {
        float B1[9], B2[9];
        #pragma unroll
        for (int i = 0; i < 3; ++i)
            #pragma unroll
            for (int j = 0; j < 3; ++j) {
                B1[i*3+j] = fmaf(A1[i*3], A1[j], fmaf(A1[i*3+1], A1[3+j], A1[i*3+2]*A1[6+j]));
                B2[i*3+j] = fmaf(A2[i*3], A2[j], fmaf(A2[i*3+1], A2[3+j], A2[i*3+2]*A2[6+j]));
            }
        #pragma unroll
        for (int i = 0; i < 9; ++i) { A1[i] = B1[i]; A2[i] = B2[i]; }
    }
    #pragma unroll
    for (int i = 0; i < 3; ++i)
        #pragma unroll
        for (int j = 0; j < 3; ++j)
            A2q[i*3+j] = fmaf(A2[i*3], A2[j], fmaf(A2[i*3+1], A2[3+j], A2[i*3+2]*A2[6+j]));
    __syncthreads();

    auto unpack = [](uint2 pk) -> float4 {
        const __half2 h01 = __builtin_bit_cast(__half2, pk.x);
        const __half2 h23 = __builtin_bit_cast(__half2, pk.y);
        return make_float4(__half2float(h01.x), __half2float(h01.y),
                           __half2float(h23.x), __half2float(h23.y));
    };
    auto whf = [](float y) -> float {   // -elu(-10/11 y) = med3(ky, 1-e^-ky, 0)
        const float t1 = 0.9090909090909091f * y;
        const float e  = 1.f - __expf(-t1);
        return __builtin_amdgcn_fmed3f(t1, e, 0.f);
    };

    float arr[32];                       // y1 local, overwritten by y2 local

    // ---- pass 1: stage-1 local (zero y-init, exact u), chunk c -------------
    {
        float u_m1 = 0.f, u_m2 = 0.f, u_m3 = 0.f;
        if (c > 0) {                     // u[32c-4 .. 32c-1] quad
            const int km1 = (c - 1) >> 1;
            const int mm1 = 8 * ((c - 1) & 1) + 7;
            const float4 ut = unpack(u4[mm1 * 256 + (km1 ^ mm1)]);
            u_m1 = ut.w; u_m2 = ut.z; u_m3 = ut.y;
        }
        float yr1 = 0.f, yr2 = 0.f, yr3 = 0.f;
        #pragma unroll
        for (int g = 0; g < 8; ++g) {
            const int m  = 8 * (c & 1) + g;
            const int kk = c >> 1;
            const float4 uu = unpack(u4[m * 256 + (kk ^ m)]);
            const float us[4] = {uu.x, uu.y, uu.z, uu.w};
            #pragma unroll
            for (int e = 0; e < 4; ++e) {
                const float x = fmaf(b12, u_m3, fmaf(b11, u_m2, b10 * u_m1));
                const float y = fmaf(-a10, yr1, fmaf(-a11, yr2, fmaf(-a12, yr3, x)));
                arr[g * 4 + e] = y;
                u_m3 = u_m2; u_m2 = u_m1; u_m1 = us[e];
                yr3 = yr2; yr2 = yr1; yr1 = y;
            }
        }
        d1s[c + 2] = make_float4(yr1, yr2, yr3, 0.f);        // y[31],[30],[29]
        vts[c + 1] = make_float2(whf(yr2), whf(yr1));        // (v[-2], v[-1])
    }
    __syncthreads();

    // ---- pass 2: y1 correction + whf + stage-2 local (fused) ---------------
    {
        const float4 P = d1s[c + 1], Q = d1s[c];             // E1 = P + A1*Q
        float h1 = fmaf(A1[0], Q.x, fmaf(A1[1], Q.y, fmaf(A1[2], Q.z, P.x)));
        float h2 = fmaf(A1[3], Q.x, fmaf(A1[4], Q.y, fmaf(A1[5], Q.z, P.y)));
        float h3 = fmaf(A1[6], Q.x, fmaf(A1[7], Q.y, fmaf(A1[8], Q.z, P.z)));
        const float2 vt = vts[c];
        float v1r = vt.y, v2r = vt.x;
        float z1 = 0.f, z2 = 0.f, z3 = 0.f;
        #pragma unroll
        for (int j = 0; j < 32; ++j) {
            const float hn = fmaf(-a10, h1, fmaf(-a11, h2, -a12 * h3));
            h3 = h2; h2 = h1; h1 = hn;
            const float v = whf(arr[j] + hn);
            const float x = fmaf(b22, v2r, fmaf(b21, v1r, b20 * v));
            const float z = fmaf(-a20, z1, fmaf(-a21, z2, fmaf(-a22, z3, x)));
            v2r = v1r; v1r = v;
            z3 = z2; z2 = z1; z1 = z;
            arr[j] = z;                                      // y2 local
        }
        d2s[c + 3] = make_float4(z1, z2, z3, 0.f);
    }
    __syncthreads();

    // ---- pass 3: E2 correction in place ------------------------------------
    {
        const float4 R = d2s[c + 2], S = d2s[c + 1], Tt = d2s[c];
        float g1 = fmaf(A2[0], S.x, fmaf(A2[1], S.y, fmaf(A2[2], S.z,
                   fmaf(A2q[0], Tt.x, fmaf(A2q[1], Tt.y, fmaf(A2q[2], Tt.z, R.x))))));
        float g2 = fmaf(A2[3], S.x, fmaf(A2[4], S.y, fmaf(A2[5], S.z,
                   fmaf(A2q[3], Tt.x, fmaf(A2q[4], Tt.y, fmaf(A2q[5], Tt.z, R.y))))));
        float g3 = fmaf(A2[6], S.x, fmaf(A2[7], S.y, fmaf(A2[8], S.z,
                   fmaf(A2q[6], Tt.x, fmaf(A2q[7], Tt.y, fmaf(A2q[8], Tt.z, R.z))))));
        #pragma unroll
        for (int j = 0; j < 32; ++j) {
            const float gn = fmaf(-a20, g1, fmaf(-a21, g2, -a22 * g3));
            g3 = g2; g2 = g1; g1 = gn;
            arr[j] += gn;
        }
    }

    // ---- store: 2 passes of 256 chunks via swizzled o_st (aliases u4) ------
    // NT stores: output is dead-on-arrival for this kernel; keep it from
    // evicting the L2/L3 read working set.
    #pragma unroll
    for (int p = 0; p < 2; ++p) {
        if ((c >> 8) == p) {
            #pragma unroll
            for (int q = 0; q < 8; ++q)
                o_st[(c & 255) * 8 + (q ^ (c & 7))] =
                    make_float4(arr[4*q], arr[4*q+1], arr[4*q+2], arr[4*q+3]);
        }
        __syncthreads();
        #pragma unroll
        for (int s = 0; s < 4; ++s) {
            const int f = s * 512 + c;          // 2048 float4 per pass
            const int k = f >> 3, q = f & 7;
            const floatx4 ov = __builtin_bit_cast(floatx4, o_st[k * 8 + (q ^ (k & 7))]);
            __builtin_nontemporal_store(ov,
                reinterpret_cast<floatx4*>(orow + (p * 256 + k) * 32 + q * 4));
        }
        if (p == 0) __syncthreads();
    }
}

extern "C" void kernel_launch(void* const* d_in, const int* in_sizes, int n_in,
                              void* d_out, int out_size, void* d_ws, size_t ws_size,
                              hipStream_t stream) {
    const float* u  = (const float*)d_in[0];
    const float* b1 = (const float*)d_in[1];
    const float* a1 = (const float*)d_in[2];
    const float* b2 = (const float*)d_in[3];
    const float* a2 = (const float*)d_in[4];
    float* out = (float*)d_out;

    const int B = in_sizes[0] / T_LEN;   // 512
    whsys_kernel<<<B, NTH, 0, stream>>>(u, b1, a1, b2, a2, out);
}